// Round 3
// baseline (1433.376 us; speedup 1.0000x reference)
//
#include <hip/hip_runtime.h>
#include <math.h>

// ---------------------------------------------------------------------------
// CausalAttention fp32 baseline.
//   q = x @ Wq ; k = x @ Wk ; v = x @ Wv          (Wq/Wk/Wv are [d_in, d_out])
//   S = q @ k^T / sqrt(D)  (causal masked)
//   P = softmax(S) ; out = P @ v
// All fp32 on the vector ALU (no fp32 MFMA on CDNA4). Correctness-first
// baseline to establish timing + counters + validation tolerance.
// (Round 3 resubmission — rounds 0/1/2 died on infra before the source was
//  ever sent to the container; error invariant to kernel content.)
// ---------------------------------------------------------------------------

#define BM 128
#define BN 128
#define BK 16

// C[M,N] = alpha * A[M,K] * B
//   TRANSB=false : B stored [K,N]
//   TRANSB=true  : B stored [N,K]
// MODE 0: plain GEMM
// MODE 1: causal scores — skip blocks entirely above the diagonal
// MODE 2: PV — clip K-loop at kend = m0+BM (attn weights are 0 beyond)
template <bool TRANSB, int MODE>
__global__ __launch_bounds__(256) void gemm_f32(
    const float* __restrict__ A, const float* __restrict__ Bm,
    float* __restrict__ C, int M, int N, int K, float alpha,
    long long sA, long long sB, long long sC)
{
    A  += (long long)blockIdx.z * sA;
    Bm += (long long)blockIdx.z * sB;
    C  += (long long)blockIdx.z * sC;

    const int m0 = blockIdx.y * BM;
    const int n0 = blockIdx.x * BN;
    if (MODE == 1 && n0 > m0 + (BM - 1)) return;  // fully masked block
    int kend = K;
    if (MODE == 2) kend = min(K, m0 + BM);        // multiple of BK by construction

    __shared__ float As[BK][BM + 4];
    __shared__ float Bs[BK][BN + 4];

    const int tid = threadIdx.x;
    const int tx  = tid & 15;   // column group
    const int ty  = tid >> 4;   // row group

    float acc[8][8];
#pragma unroll
    for (int i = 0; i < 8; ++i)
#pragma unroll
        for (int j = 0; j < 8; ++j) acc[i][j] = 0.0f;

    for (int k0 = 0; k0 < kend; k0 += BK) {
        // ---- stage A tile [BM x BK] as As[k][m]
#pragma unroll
        for (int it = 0; it < (BM * BK) / 256; ++it) {
            int idx = tid + it * 256;
            int r = idx >> 4;       // 0..127
            int c = idx & 15;       // 0..15
            As[c][r] = A[(size_t)(m0 + r) * K + (k0 + c)];
        }
        // ---- stage B tile as Bs[k][n]
        if (TRANSB) {
#pragma unroll
            for (int it = 0; it < (BN * BK) / 256; ++it) {
                int idx = tid + it * 256;
                int n = idx >> 4;   // 0..127
                int c = idx & 15;   // 0..15
                Bs[c][n] = Bm[(size_t)(n0 + n) * K + (k0 + c)];
            }
        } else {
#pragma unroll
            for (int it = 0; it < (BK * BN) / 256; ++it) {
                int idx = tid + it * 256;
                int r = idx >> 7;   // 0..15
                int c = idx & 127;  // 0..127
                Bs[r][c] = Bm[(size_t)(k0 + r) * N + (n0 + c)];
            }
        }
        __syncthreads();

#pragma unroll
        for (int kk = 0; kk < BK; ++kk) {
            float a[8], b[8];
#pragma unroll
            for (int j = 0; j < 4; ++j) {
                a[j]     = As[kk][ty * 4 + j];
                a[j + 4] = As[kk][ty * 4 + 64 + j];
                b[j]     = Bs[kk][tx * 4 + j];
                b[j + 4] = Bs[kk][tx * 4 + 64 + j];
            }
#pragma unroll
            for (int i = 0; i < 8; ++i)
#pragma unroll
                for (int j = 0; j < 8; ++j)
                    acc[i][j] += a[i] * b[j];
        }
        __syncthreads();
    }

#pragma unroll
    for (int i = 0; i < 8; ++i) {
        int r = m0 + ty * 4 + ((i < 4) ? i : (64 + i - 4));
#pragma unroll
        for (int j = 0; j < 8; ++j) {
            int c = n0 + tx * 4 + ((j < 4) ? j : (64 + j - 4));
            C[(size_t)r * N + c] = alpha * acc[i][j];
        }
    }
}

// One block per (row, batch). Causal softmax in-place on S.
// Masked entries (col > row) are written as 0 so the PV GEMM can read them.
__global__ __launch_bounds__(256) void causal_softmax(
    float* __restrict__ S, int n, long long sBatch)
{
    float* Srow = S + (long long)blockIdx.y * sBatch + (size_t)blockIdx.x * n;
    const int row     = blockIdx.x;
    const int allowed = row + 1;
    const int tid     = threadIdx.x;

    __shared__ float red[256];

    // 1) max over allowed prefix
    float m = -1e30f;
    for (int j = tid; j < allowed; j += 256) m = fmaxf(m, Srow[j]);
    red[tid] = m;
    __syncthreads();
    for (int s = 128; s > 0; s >>= 1) {
        if (tid < s) red[tid] = fmaxf(red[tid], red[tid + s]);
        __syncthreads();
    }
    m = red[0];
    __syncthreads();

    // 2) exp + sum
    float sum = 0.0f;
    for (int j = tid; j < allowed; j += 256) {
        float e = __expf(Srow[j] - m);
        Srow[j] = e;
        sum += e;
    }
    red[tid] = sum;
    __syncthreads();
    for (int s = 128; s > 0; s >>= 1) {
        if (tid < s) red[tid] += red[tid + s];
        __syncthreads();
    }
    const float inv = 1.0f / red[0];

    // 3) normalize, zero the masked tail
    for (int j = tid; j < n; j += 256)
        Srow[j] = (j < allowed) ? Srow[j] * inv : 0.0f;
}

extern "C" void kernel_launch(void* const* d_in, const int* in_sizes, int n_in,
                              void* d_out, int out_size, void* d_ws, size_t ws_size,
                              hipStream_t stream)
{
    (void)in_sizes; (void)n_in; (void)out_size;

    const float* x  = (const float*)d_in[0];
    const float* Wq = (const float*)d_in[1];
    const float* Wk = (const float*)d_in[2];
    const float* Wv = (const float*)d_in[3];
    float* out = (float*)d_out;

    const int NB = 4, S = 2048, D = 1024;
    const long long qkv1 = (long long)S * D;   // per-batch Q/K/V elems
    const long long s1   = (long long)S * S;   // per-batch score elems
    const float scale = 0.03125f;              // 1/sqrt(1024)

    const size_t need_big = (size_t)(3 * NB * qkv1 + NB * s1) * 4;  // ~168 MB
    const size_t need_mid = (size_t)(3 * NB * qkv1 + s1) * 4;       // ~117 MB

    dim3 blk(256);

    if (ws_size >= need_big) {
        // Fully batched: Q|K|V (all batches) + S (all batches)
        float* Q  = (float*)d_ws;
        float* Kp = Q  + NB * qkv1;
        float* V  = Kp + NB * qkv1;
        float* Sc = V  + NB * qkv1;

        dim3 gp(D / BN, (NB * S) / BM, 1);
        gemm_f32<false, 0><<<gp, blk, 0, stream>>>(x, Wq, Q,  NB * S, D, D, 1.0f, 0, 0, 0);
        gemm_f32<false, 0><<<gp, blk, 0, stream>>>(x, Wk, Kp, NB * S, D, D, 1.0f, 0, 0, 0);
        gemm_f32<false, 0><<<gp, blk, 0, stream>>>(x, Wv, V,  NB * S, D, D, 1.0f, 0, 0, 0);

        dim3 gs(S / BN, S / BM, NB);
        gemm_f32<true, 1><<<gs, blk, 0, stream>>>(Q, Kp, Sc, S, S, D, scale, qkv1, qkv1, s1);

        causal_softmax<<<dim3(S, NB), blk, 0, stream>>>(Sc, S, s1);

        dim3 gv(D / BN, S / BM, NB);
        gemm_f32<false, 2><<<gv, blk, 0, stream>>>(Sc, V, out, S, D, S, 1.0f, s1, qkv1, qkv1);
    } else if (ws_size >= need_mid) {
        // Q/K/V all batches, score buffer reused per batch (serialized)
        float* Q  = (float*)d_ws;
        float* Kp = Q  + NB * qkv1;
        float* V  = Kp + NB * qkv1;
        float* Sc = V  + NB * qkv1;

        dim3 gp(D / BN, (NB * S) / BM, 1);
        gemm_f32<false, 0><<<gp, blk, 0, stream>>>(x, Wq, Q,  NB * S, D, D, 1.0f, 0, 0, 0);
        gemm_f32<false, 0><<<gp, blk, 0, stream>>>(x, Wk, Kp, NB * S, D, D, 1.0f, 0, 0, 0);
        gemm_f32<false, 0><<<gp, blk, 0, stream>>>(x, Wv, V,  NB * S, D, D, 1.0f, 0, 0, 0);

        dim3 gs(S / BN, S / BM, 1);
        dim3 gv(D / BN, S / BM, 1);
        for (int b = 0; b < NB; ++b) {
            gemm_f32<true, 1><<<gs, blk, 0, stream>>>(Q + b * qkv1, Kp + b * qkv1, Sc,
                                                      S, S, D, scale, 0, 0, 0);
            causal_softmax<<<dim3(S, 1), blk, 0, stream>>>(Sc, S, 0);
            gemm_f32<false, 2><<<gv, blk, 0, stream>>>(Sc, V + b * qkv1, out + b * qkv1,
                                                       S, D, S, 1.0f, 0, 0, 0);
        }
    } else {
        // Fully per-batch serialized: Q|K|V (one batch) + S (one batch) ~42 MB
        float* Q  = (float*)d_ws;
        float* Kp = Q  + qkv1;
        float* V  = Kp + qkv1;
        float* Sc = V  + qkv1;

        dim3 gp(D / BN, S / BM, 1);
        dim3 gs(S / BN, S / BM, 1);
        dim3 gv(D / BN, S / BM, 1);
        for (int b = 0; b < NB; ++b) {
            const float* xb = x + b * qkv1;
            gemm_f32<false, 0><<<gp, blk, 0, stream>>>(xb, Wq, Q,  S, D, D, 1.0f, 0, 0, 0);
            gemm_f32<false, 0><<<gp, blk, 0, stream>>>(xb, Wk, Kp, S, D, D, 1.0f, 0, 0, 0);
            gemm_f32<false, 0><<<gp, blk, 0, stream>>>(xb, Wv, V,  S, D, D, 1.0f, 0, 0, 0);
            gemm_f32<true, 1><<<gs, blk, 0, stream>>>(Q, Kp, Sc, S, S, D, scale, 0, 0, 0);
            causal_softmax<<<dim3(S, 1), blk, 0, stream>>>(Sc, S, 0);
            gemm_f32<false, 2><<<gv, blk, 0, stream>>>(Sc, V, out + b * qkv1,
                                                       S, D, S, 1.0f, 0, 0, 0);
        }
    }
}

// Round 4
// 269.800 us; speedup vs baseline: 5.3127x; 5.3127x over previous
//
#include <hip/hip_runtime.h>
#include <math.h>

// ---------------------------------------------------------------------------
// CausalAttention — bf16 MFMA pipeline (round 4).
//   cvt:   x -> bf16; W -> bf16 transposed [n][k]
//   proj:  Q,K bf16 [s][d]; V split hi/lo bf16, TRANSPOSED [d][s] per batch
//   QK^T:  bf16 MFMA, fp32 scores, causal block-skip, alpha=1/32
//   softmax: fp32 in-place -> bf16 P (row stride 4096 ushorts, in Sc memory)
//   PV:    P·(Vhi+Vlo) -> fp32 out, K-loop clipped at block diagonal
// GEMM structure: 128x128 tile, BK=32, 4 waves x (64x64), 16x16x32 bf16 MFMA,
// global_load_lds width=16 staging (m97 structure).
// ---------------------------------------------------------------------------

typedef float  f32x4  __attribute__((ext_vector_type(4)));
typedef int    i32x4  __attribute__((ext_vector_type(4)));
typedef __bf16 bf16x8 __attribute__((ext_vector_type(8)));

__device__ inline ushort f2bf(float f) {
    union { float f; unsigned u; } a; a.f = f;
    unsigned u = a.u;
    return (ushort)((u + 0x7fffu + ((u >> 16) & 1u)) >> 16);  // RNE
}
__device__ inline float bf2f(ushort h) {
    union { unsigned u; float f; } a; a.u = ((unsigned)h) << 16;
    return a.f;
}
__device__ inline bf16x8 as_bf(i32x4 v) {
    union { i32x4 i; bf16x8 b; } u; u.i = v; return u.b;
}

#define GLDS(gp, lp)                                                         \
    __builtin_amdgcn_global_load_lds(                                        \
        (const __attribute__((address_space(1))) void*)(gp),                 \
        (__attribute__((address_space(3))) void*)(lp), 16, 0, 0)

#define TIL 128
#define BKK 32

// MODE 0: plain   MODE 1: causal block-skip (scores)   MODE 2: k-clip (PV)
// OUT  0: fp32 C[r][c]=v*alpha
// OUT  1: bf16 C[r][c]
// OUT  2: split bf16 transposed per batch: Ch/Cl[b][c][s], b=r>>11, s=r&2047
template <int MODE, int OUT, bool TWOB>
__global__ __launch_bounds__(256) void gemm_bf16(
    const ushort* __restrict__ A, const ushort* __restrict__ B0,
    const ushort* __restrict__ B1, float* __restrict__ Cf,
    ushort* __restrict__ Ch, ushort* __restrict__ Cl,
    int M, int N, int K, int lda, int ldb,
    long long sA, long long sB, long long sC, float alpha)
{
    A  += (long long)blockIdx.z * sA;
    B0 += (long long)blockIdx.z * sB;
    const ushort* B1b = TWOB ? (B1 + (long long)blockIdx.z * sB) : nullptr;

    const int m0 = blockIdx.y * TIL;
    const int n0 = blockIdx.x * TIL;
    if (MODE == 1 && n0 > m0 + (TIL - 1)) return;   // fully masked score block
    int kend = K;
    if (MODE == 2) kend = min(K, m0 + TIL);         // attn weights 0 beyond

    __shared__ ushort As[TIL * BKK];
    __shared__ ushort Bs[TIL * BKK];
    __shared__ ushort Bs2[TWOB ? TIL * BKK : 16];

    const int tid = threadIdx.x;
    const int l   = tid & 63;
    const int w   = tid >> 6;       // wave 0..3
    const int g   = l >> 4;         // 0..3
    const int r16 = l & 15;
    const int wr  = w >> 1, wc = w & 1;   // wave -> 64x64 quadrant

    f32x4 acc[4][4];
#pragma unroll
    for (int mi = 0; mi < 4; ++mi)
#pragma unroll
        for (int ni = 0; ni < 4; ++ni)
            acc[mi][ni] = (f32x4){0.f, 0.f, 0.f, 0.f};

    // staging: wave w covers rows w*32 .. w*32+31 (two 16-row issues)
    const int srow = w * 32 + (l >> 2);   // +16 on second issue
    const int scol = (l & 3) * 8;
    const ushort* gA  = A   + (size_t)(m0 + srow) * lda + scol;
    const ushort* gB  = B0  + (size_t)(n0 + srow) * ldb + scol;
    const ushort* gB1 = TWOB ? (B1b + (size_t)(n0 + srow) * ldb + scol) : nullptr;
    ushort* lA = As + (w * 32) * BKK;     // wave-uniform dest (lane x 16B linear)
    ushort* lB = Bs + (w * 32) * BKK;
    ushort* lB2 = TWOB ? (Bs2 + (w * 32) * BKK) : nullptr;

    for (int k0 = 0; k0 < kend; k0 += BKK) {
        GLDS(gA + k0, lA);
        GLDS(gA + k0 + (size_t)16 * lda, lA + 16 * BKK);
        GLDS(gB + k0, lB);
        GLDS(gB + k0 + (size_t)16 * ldb, lB + 16 * BKK);
        if (TWOB) {
            GLDS(gB1 + k0, lB2);
            GLDS(gB1 + k0 + (size_t)16 * ldb, lB2 + 16 * BKK);
        }
        __syncthreads();

        i32x4 av[4], bv[4];
#pragma unroll
        for (int mi = 0; mi < 4; ++mi)
            av[mi] = *(const i32x4*)(As + (wr * 64 + mi * 16 + r16) * BKK + g * 8);
#pragma unroll
        for (int ni = 0; ni < 4; ++ni)
            bv[ni] = *(const i32x4*)(Bs + (wc * 64 + ni * 16 + r16) * BKK + g * 8);

#pragma unroll
        for (int mi = 0; mi < 4; ++mi)
#pragma unroll
            for (int ni = 0; ni < 4; ++ni)
                acc[mi][ni] = __builtin_amdgcn_mfma_f32_16x16x32_bf16(
                    as_bf(av[mi]), as_bf(bv[ni]), acc[mi][ni], 0, 0, 0);

        if (TWOB) {
            i32x4 bw[4];
#pragma unroll
            for (int ni = 0; ni < 4; ++ni)
                bw[ni] = *(const i32x4*)(Bs2 + (wc * 64 + ni * 16 + r16) * BKK + g * 8);
#pragma unroll
            for (int mi = 0; mi < 4; ++mi)
#pragma unroll
                for (int ni = 0; ni < 4; ++ni)
                    acc[mi][ni] = __builtin_amdgcn_mfma_f32_16x16x32_bf16(
                        as_bf(av[mi]), as_bf(bw[ni]), acc[mi][ni], 0, 0, 0);
        }
        __syncthreads();
    }

    // epilogue: C/D mapping col=lane&15, row=(lane>>4)*4+reg  [m89-verified]
#pragma unroll
    for (int mi = 0; mi < 4; ++mi) {
#pragma unroll
        for (int ni = 0; ni < 4; ++ni) {
#pragma unroll
            for (int rr = 0; rr < 4; ++rr) {
                const int gr = m0 + wr * 64 + mi * 16 + g * 4 + rr;
                const int gc = n0 + wc * 64 + ni * 16 + r16;
                const float v = acc[mi][ni][rr] * alpha;
                if (OUT == 0) {
                    Cf[(long long)blockIdx.z * sC + (size_t)gr * N + gc] = v;
                } else if (OUT == 1) {
                    Ch[(long long)blockIdx.z * sC + (size_t)gr * N + gc] = f2bf(v);
                } else {  // split-transposed (V): batch from row, S=2048 hard
                    const int bb = gr >> 11, ss = gr & 2047;
                    const size_t di = (size_t)bb * (size_t)N * 2048
                                    + (size_t)gc * 2048 + ss;
                    const ushort hi = f2bf(v);
                    Ch[di] = hi;
                    Cl[di] = f2bf(v - bf2f(hi));
                }
            }
        }
    }
}

// fp32 scores -> bf16 P in place. Row j: read fp32 [0..j], write 2048 bf16
// (masked tail = 0) at the same row start, stride 4096 ushorts per row.
__global__ __launch_bounds__(256) void softmax_bf16(float* __restrict__ Sc)
{
    const int row = blockIdx.x;
    float* base = Sc + ((size_t)blockIdx.y * 2048 + row) * 2048;
    const int tid = threadIdx.x;

    float v[8];
#pragma unroll
    for (int i = 0; i < 8; ++i) {
        const int j = tid + i * 256;
        v[i] = (j <= row) ? base[j] : -INFINITY;
    }

    __shared__ float red[256];
    float m = -INFINITY;
#pragma unroll
    for (int i = 0; i < 8; ++i) m = fmaxf(m, v[i]);
    red[tid] = m;
    __syncthreads();
    for (int s = 128; s > 0; s >>= 1) {
        if (tid < s) red[tid] = fmaxf(red[tid], red[tid + s]);
        __syncthreads();
    }
    m = red[0];
    __syncthreads();

    float e[8], sum = 0.f;
#pragma unroll
    for (int i = 0; i < 8; ++i) {
        const int j = tid + i * 256;
        e[i] = (j <= row) ? __expf(v[i] - m) : 0.f;
        sum += e[i];
    }
    red[tid] = sum;
    __syncthreads();
    for (int s = 128; s > 0; s >>= 1) {
        if (tid < s) red[tid] += red[tid + s];
        __syncthreads();
    }
    const float inv = 1.f / red[0];

    ushort* pb = (ushort*)base;
#pragma unroll
    for (int i = 0; i < 8; ++i) {
        const int j = tid + i * 256;
        pb[j] = f2bf(e[i] * inv);
    }
}

__global__ void cvt_x(const float4* __restrict__ x, ushort4* __restrict__ o, int n4)
{
    const int i = blockIdx.x * 256 + threadIdx.x;
    if (i < n4) {
        const float4 f = x[i];
        ushort4 u;
        u.x = f2bf(f.x); u.y = f2bf(f.y); u.z = f2bf(f.z); u.w = f2bf(f.w);
        o[i] = u;
    }
}

// W [1024][1024] fp32 -> Wt [n][k] bf16 (transpose-convert)
__global__ __launch_bounds__(256) void cvt_wt(const float* __restrict__ W,
                                              ushort* __restrict__ Wt)
{
    __shared__ float t[32][33];
    const int tx = threadIdx.x & 31, ty = threadIdx.x >> 5;   // ty 0..7
    const int c = blockIdx.x * 32 + tx;
    const int rbase = blockIdx.y * 32;
#pragma unroll
    for (int i = 0; i < 4; ++i)
        t[ty + i * 8][tx] = W[(size_t)(rbase + ty + i * 8) * 1024 + c];
    __syncthreads();
    const int kT = blockIdx.y * 32 + tx;
    const int nT = blockIdx.x * 32;
#pragma unroll
    for (int i = 0; i < 4; ++i)
        Wt[(size_t)(nT + ty + i * 8) * 1024 + kT] = f2bf(t[tx][ty + i * 8]);
}

extern "C" void kernel_launch(void* const* d_in, const int* in_sizes, int n_in,
                              void* d_out, int out_size, void* d_ws, size_t ws_size,
                              hipStream_t stream)
{
    (void)in_sizes; (void)n_in; (void)out_size; (void)ws_size;

    const float* x  = (const float*)d_in[0];
    const float* Wq = (const float*)d_in[1];
    const float* Wk = (const float*)d_in[2];
    const float* Wv = (const float*)d_in[3];
    float* out = (float*)d_out;

    const int NB = 4, S = 2048, D = 1024;
    const long long SD = (long long)S * D;      // 2,097,152
    const long long NSD = NB * SD;              // 8,388,608

    // workspace layout (150 MB total, all chunks 16B-aligned)
    ushort* xb  = (ushort*)d_ws;
    ushort* Wqt = xb  + NSD;
    ushort* Wkt = Wqt + (size_t)D * D;
    ushort* Wvt = Wkt + (size_t)D * D;
    ushort* Qb  = Wvt + (size_t)D * D;
    ushort* Kb  = Qb  + NSD;
    ushort* Vh  = Kb  + NSD;
    ushort* Vl  = Vh  + NSD;
    float*  Sc  = (float*)(Vl + NSD);           // NB*S*S fp32 (P overlays bf16)

    dim3 blk(256);

    // 1) conversions
    cvt_x<<<dim3((unsigned)(NSD / 4 / 256)), blk, 0, stream>>>(
        (const float4*)x, (ushort4*)xb, (int)(NSD / 4));
    cvt_wt<<<dim3(32, 32), blk, 0, stream>>>(Wq, Wqt);
    cvt_wt<<<dim3(32, 32), blk, 0, stream>>>(Wk, Wkt);
    cvt_wt<<<dim3(32, 32), blk, 0, stream>>>(Wv, Wvt);

    // 2) projections (batches folded into M=8192)
    dim3 gp(D / TIL, (unsigned)(NB * S / TIL), 1);
    gemm_bf16<0, 1, false><<<gp, blk, 0, stream>>>(
        xb, Wqt, nullptr, nullptr, Qb, nullptr,
        NB * S, D, D, D, D, 0, 0, 0, 1.f);
    gemm_bf16<0, 1, false><<<gp, blk, 0, stream>>>(
        xb, Wkt, nullptr, nullptr, Kb, nullptr,
        NB * S, D, D, D, D, 0, 0, 0, 1.f);
    gemm_bf16<0, 2, false><<<gp, blk, 0, stream>>>(
        xb, Wvt, nullptr, nullptr, Vh, Vl,
        NB * S, D, D, D, D, 0, 0, 0, 1.f);

    // 3) scores = Q K^T / 32, causal block-skip
    dim3 gs(S / TIL, S / TIL, NB);
    gemm_bf16<1, 0, false><<<gs, blk, 0, stream>>>(
        Qb, Kb, nullptr, Sc, nullptr, nullptr,
        S, S, D, D, D, SD, SD, (long long)S * S, 0.03125f);

    // 4) softmax fp32 -> bf16 P in place
    softmax_bf16<<<dim3(S, NB), blk, 0, stream>>>(Sc);

    // 5) out = P (Vhi + Vlo), k-clipped at the block diagonal
    dim3 gv(D / TIL, S / TIL, NB);
    gemm_bf16<2, 0, true><<<gv, blk, 0, stream>>>(
        (const ushort*)Sc, Vh, Vl, out, nullptr, nullptr,
        S, D, S, 2 * S, S, (long long)S * 2 * S, SD, SD, 1.f);
}

// Round 5
// 236.622 us; speedup vs baseline: 6.0577x; 1.1402x over previous
//
#include <hip/hip_runtime.h>
#include <math.h>

// ---------------------------------------------------------------------------
// CausalAttention — bf16 MFMA pipeline, round 5.
//   cvt:   x -> bf16; Wq|Wk|Wv -> one packed bf16 Wt3 [3072][1024] (transposed)
//   proj:  ONE GEMM  [8192 x 3072 x 1024] -> Q,K bf16 [s][d]; V bf16 [b][d][s]
//   QK^T:  bf16 MFMA -> fp32 scores (L3-resident), causal block-skip
//   softmax: fp32 -> bf16 P in place (row stride 4096 ushorts)
//   PV:    P·V^T -> fp32 out, K-loop clipped at block diagonal (single V now)
// GEMM: 128x128 tile, BK=32, 4 waves x 64x64, 16x16x32 bf16 MFMA,
// global_load_lds w=16 staging with chunk-XOR LDS swizzle:
//   64B rows => bank group (16r+4c)%32 was 2 groups/16 lanes (8-way conflict);
//   c ^= (r>>1)&3 spreads to all 8 groups (2-way = free). Applied as
//   pre-swizzled per-lane GLOBAL source + swizzled ds_read (linear LDS dest).
// ---------------------------------------------------------------------------

typedef float  f32x4  __attribute__((ext_vector_type(4)));
typedef int    i32x4  __attribute__((ext_vector_type(4)));
typedef __bf16 bf16x8 __attribute__((ext_vector_type(8)));

__device__ inline ushort f2bf(float f) {
    union { float f; unsigned u; } a; a.f = f;
    unsigned u = a.u;
    return (ushort)((u + 0x7fffu + ((u >> 16) & 1u)) >> 16);  // RNE
}
__device__ inline bf16x8 as_bf(i32x4 v) {
    union { i32x4 i; bf16x8 b; } u; u.i = v; return u.b;
}

#define GLDS(gp, lp)                                                         \
    __builtin_amdgcn_global_load_lds(                                        \
        (const __attribute__((address_space(1))) void*)(gp),                 \
        (__attribute__((address_space(3))) void*)(lp), 16, 0, 0)

#define TIL 128
#define BKK 32

// 16B-chunk XOR swizzle within a 64B LDS row (involution)
__device__ inline int swz(int row, int c) { return c ^ ((row >> 1) & 3); }

// MODE 0: plain  1: causal block-skip (scores)  2: k-clip (PV)
// OUT  0: fp32 C[z][r][c] = v*alpha
// OUT  3: merged QKV epilogue (region by n0: Q | K | V-transposed)
template <int MODE, int OUT>
__global__ __launch_bounds__(256) void gemm_bf16(
    const ushort* __restrict__ A, const ushort* __restrict__ B0,
    float* __restrict__ Cf, ushort* __restrict__ Cq,
    ushort* __restrict__ Ck, ushort* __restrict__ Cv,
    int N, int K, int lda, int ldb,
    long long sA, long long sB, long long sC, float alpha)
{
    A  += (long long)blockIdx.z * sA;
    B0 += (long long)blockIdx.z * sB;

    const int m0 = blockIdx.y * TIL;
    const int n0 = blockIdx.x * TIL;
    if (MODE == 1 && n0 > m0 + (TIL - 1)) return;   // fully masked score block
    int kend = K;
    if (MODE == 2) kend = min(K, m0 + TIL);         // attn weights 0 beyond

    __shared__ ushort As[TIL * BKK];
    __shared__ ushort Bs[TIL * BKK];

    const int tid = threadIdx.x;
    const int l   = tid & 63;
    const int w   = tid >> 6;       // wave 0..3
    const int g   = l >> 4;         // chunk 0..3
    const int r16 = l & 15;
    const int wr  = w >> 1, wc = w & 1;   // wave -> 64x64 quadrant

    f32x4 acc[4][4];
#pragma unroll
    for (int mi = 0; mi < 4; ++mi)
#pragma unroll
        for (int ni = 0; ni < 4; ++ni)
            acc[mi][ni] = (f32x4){0.f, 0.f, 0.f, 0.f};

    // staging: wave w covers rows w*32..+31 (two 16-row issues).
    // LDS dest linear (base + lane*16B); global source chunk pre-swizzled so
    // LDS chunk c holds global chunk swz(r,c). (r+16 preserves (r>>1)&3.)
    const int srow = w * 32 + (l >> 2);
    const int cg   = swz(srow, l & 3);
    const ushort* gA = A  + (size_t)(m0 + srow) * lda + cg * 8;
    const ushort* gB = B0 + (size_t)(n0 + srow) * ldb + cg * 8;
    ushort* lA = As + w * 32 * BKK;
    ushort* lB = Bs + w * 32 * BKK;

    for (int k0 = 0; k0 < kend; k0 += BKK) {
        GLDS(gA + k0, lA);
        GLDS(gA + k0 + (size_t)16 * lda, lA + 16 * BKK);
        GLDS(gB + k0, lB);
        GLDS(gB + k0 + (size_t)16 * ldb, lB + 16 * BKK);
        __syncthreads();

        i32x4 av[4], bv[4];
#pragma unroll
        for (int mi = 0; mi < 4; ++mi) {
            const int r = wr * 64 + mi * 16 + r16;
            av[mi] = *(const i32x4*)(As + r * BKK + swz(r, g) * 8);
        }
#pragma unroll
        for (int ni = 0; ni < 4; ++ni) {
            const int r = wc * 64 + ni * 16 + r16;
            bv[ni] = *(const i32x4*)(Bs + r * BKK + swz(r, g) * 8);
        }

#pragma unroll
        for (int mi = 0; mi < 4; ++mi)
#pragma unroll
            for (int ni = 0; ni < 4; ++ni)
                acc[mi][ni] = __builtin_amdgcn_mfma_f32_16x16x32_bf16(
                    as_bf(av[mi]), as_bf(bv[ni]), acc[mi][ni], 0, 0, 0);
        __syncthreads();
    }

    // epilogue: C/D mapping col=lane&15, row=(lane>>4)*4+reg  [m89-verified]
#pragma unroll
    for (int mi = 0; mi < 4; ++mi) {
#pragma unroll
        for (int ni = 0; ni < 4; ++ni) {
#pragma unroll
            for (int rr = 0; rr < 4; ++rr) {
                const int gr = m0 + wr * 64 + mi * 16 + g * 4 + rr;
                const int gc = n0 + wc * 64 + ni * 16 + r16;
                const float v = acc[mi][ni][rr] * alpha;
                if (OUT == 0) {
                    Cf[(long long)blockIdx.z * sC + (size_t)gr * N + gc] = v;
                } else {  // merged QKV; region uniform per block (TIL<1024)
                    if (n0 < 1024) {
                        Cq[(size_t)gr * 1024 + gc] = f2bf(v);
                    } else if (n0 < 2048) {
                        Ck[(size_t)gr * 1024 + (gc - 1024)] = f2bf(v);
                    } else {  // V transposed per batch: [b][d][s], S=2048
                        const int d = gc - 2048, bb = gr >> 11, ss = gr & 2047;
                        Cv[(size_t)bb * 2097152 + (size_t)d * 2048 + ss] = f2bf(v);
                    }
                }
            }
        }
    }
}

// fp32 scores -> bf16 P in place. Row stride 4096 ushorts (= fp32 row size);
// writes full 2048 bf16 incl. zeroed causal tail.
__global__ __launch_bounds__(256) void softmax_bf16(float* __restrict__ Sc)
{
    const int row = blockIdx.x;
    float* base = Sc + ((size_t)blockIdx.y * 2048 + row) * 2048;
    const int tid = threadIdx.x;

    float v[8];
#pragma unroll
    for (int i = 0; i < 8; ++i) {
        const int j = tid + i * 256;
        v[i] = (j <= row) ? base[j] : -INFINITY;
    }

    __shared__ float red[256];
    float m = -INFINITY;
#pragma unroll
    for (int i = 0; i < 8; ++i) m = fmaxf(m, v[i]);
    red[tid] = m;
    __syncthreads();
    for (int s = 128; s > 0; s >>= 1) {
        if (tid < s) red[tid] = fmaxf(red[tid], red[tid + s]);
        __syncthreads();
    }
    m = red[0];
    __syncthreads();

    float e[8], sum = 0.f;
#pragma unroll
    for (int i = 0; i < 8; ++i) {
        const int j = tid + i * 256;
        e[i] = (j <= row) ? __expf(v[i] - m) : 0.f;
        sum += e[i];
    }
    red[tid] = sum;
    __syncthreads();
    for (int s = 128; s > 0; s >>= 1) {
        if (tid < s) red[tid] += red[tid + s];
        __syncthreads();
    }
    const float inv = 1.f / red[0];

    ushort* pb = (ushort*)base;
#pragma unroll
    for (int i = 0; i < 8; ++i) {
        const int j = tid + i * 256;
        pb[j] = f2bf(e[i] * inv);
    }
}

__global__ void cvt_x(const float4* __restrict__ x, ushort4* __restrict__ o, int n4)
{
    const int i = blockIdx.x * 256 + threadIdx.x;
    if (i < n4) {
        const float4 f = x[i];
        ushort4 u;
        u.x = f2bf(f.x); u.y = f2bf(f.y); u.z = f2bf(f.z); u.w = f2bf(f.w);
        o[i] = u;
    }
}

// W[z] [1024][1024] fp32 -> Wt3 + z*1M : bf16 [n][k] (transpose-convert)
__global__ __launch_bounds__(256) void cvt_wt(const float* __restrict__ Wq,
                                              const float* __restrict__ Wk,
                                              const float* __restrict__ Wv,
                                              ushort* __restrict__ Wt3)
{
    const float* W = (blockIdx.z == 0) ? Wq : (blockIdx.z == 1) ? Wk : Wv;
    ushort* Wt = Wt3 + (size_t)blockIdx.z * 1048576;

    __shared__ float t[32][33];
    const int tx = threadIdx.x & 31, ty = threadIdx.x >> 5;   // ty 0..7
    const int c = blockIdx.x * 32 + tx;
    const int rbase = blockIdx.y * 32;
#pragma unroll
    for (int i = 0; i < 4; ++i)
        t[ty + i * 8][tx] = W[(size_t)(rbase + ty + i * 8) * 1024 + c];
    __syncthreads();
    const int kT = blockIdx.y * 32 + tx;
    const int nT = blockIdx.x * 32;
#pragma unroll
    for (int i = 0; i < 4; ++i)
        Wt[(size_t)(nT + ty + i * 8) * 1024 + kT] = f2bf(t[tx][ty + i * 8]);
}

extern "C" void kernel_launch(void* const* d_in, const int* in_sizes, int n_in,
                              void* d_out, int out_size, void* d_ws, size_t ws_size,
                              hipStream_t stream)
{
    (void)in_sizes; (void)n_in; (void)out_size; (void)ws_size;

    const float* x  = (const float*)d_in[0];
    const float* Wq = (const float*)d_in[1];
    const float* Wk = (const float*)d_in[2];
    const float* Wv = (const float*)d_in[3];
    float* out = (float*)d_out;

    const int NB = 4, S = 2048, D = 1024;
    const long long SD  = (long long)S * D;     // 2,097,152
    const long long NSD = NB * SD;              // 8,388,608
    const long long SS  = (long long)S * S;     // 4,194,304

    // workspace (~140 MB): xb | Wt3 | Qb | Kb | Vt | Sc
    ushort* xb  = (ushort*)d_ws;
    ushort* Wt3 = xb  + NSD;                    // 3 * 1M ushorts
    ushort* Qb  = Wt3 + 3 * (size_t)D * D;
    ushort* Kb  = Qb  + NSD;
    ushort* Vt  = Kb  + NSD;
    float*  Sc  = (float*)(Vt + NSD);           // NB*S*S fp32 (P overlays bf16)

    dim3 blk(256);

    // 1) conversions
    cvt_x<<<dim3((unsigned)(NSD / 4 / 256)), blk, 0, stream>>>(
        (const float4*)x, (ushort4*)xb, (int)(NSD / 4));
    cvt_wt<<<dim3(32, 32, 3), blk, 0, stream>>>(Wq, Wk, Wv, Wt3);

    // 2) merged QKV projection: [8192 x 3072 x 1024]
    dim3 gp(3 * D / TIL, (unsigned)(NB * S / TIL), 1);
    gemm_bf16<0, 3><<<gp, blk, 0, stream>>>(
        xb, Wt3, nullptr, Qb, Kb, Vt,
        3 * D, D, D, D, 0, 0, 0, 1.f);

    // 3) scores = Q K^T / 32, causal block-skip, fp32 (L3-resident)
    dim3 gs(S / TIL, S / TIL, NB);
    gemm_bf16<1, 0><<<gs, blk, 0, stream>>>(
        Qb, Kb, Sc, nullptr, nullptr, nullptr,
        S, D, D, D, SD, SD, SS, 0.03125f);

    // 4) softmax fp32 -> bf16 P in place
    softmax_bf16<<<dim3(S, NB), blk, 0, stream>>>(Sc);

    // 5) out = P V^T, k-clipped at the block diagonal
    dim3 gv(D / TIL, S / TIL, NB);
    gemm_bf16<2, 0><<<gv, blk, 0, stream>>>(
        (const ushort*)Sc, Vt, out, nullptr, nullptr, nullptr,
        D, S, 2 * S, S, 2 * SS, SD, SD, 1.f);
}

// Round 6
// 207.201 us; speedup vs baseline: 6.9178x; 1.1420x over previous
//
#include <hip/hip_runtime.h>
#include <math.h>

// ---------------------------------------------------------------------------
// CausalAttention — bf16 MFMA pipeline, round 6.
// Changes vs round 5:
//   * T3-minimum double-buffered K-loop: STAGE(t+1) issued BEFORE compute(t),
//     ONE barrier per iter. The old code staged then immediately barriered,
//     exposing full load latency every iteration (MfmaUtil 20%).
//   * QKV projection writes ONE merged bf16 buffer [8192][3072] (branch-free,
//     coalesced epilogue). Q/K consumed as strided views (lda=3072).
//   * V transposed to Vt[b][d][s] by a dedicated 64x64 LDS transpose kernel
//     (the old in-epilogue V scatter was 64x 2B stores at 4KB stride/thread).
// GEMM core: 128x128 tile, BK=32, 4 waves x 64x64, 16x16x32 bf16 MFMA,
// global_load_lds w=16, chunk-XOR swizzle (measured 0 bank conflicts).
// ---------------------------------------------------------------------------

typedef float  f32x4  __attribute__((ext_vector_type(4)));
typedef int    i32x4  __attribute__((ext_vector_type(4)));
typedef __bf16 bf16x8 __attribute__((ext_vector_type(8)));

__device__ inline ushort f2bf(float f) {
    union { float f; unsigned u; } a; a.f = f;
    unsigned u = a.u;
    return (ushort)((u + 0x7fffu + ((u >> 16) & 1u)) >> 16);  // RNE
}
__device__ inline bf16x8 as_bf(i32x4 v) {
    union { i32x4 i; bf16x8 b; } u; u.i = v; return u.b;
}

#define GLDS(gp, lp)                                                         \
    __builtin_amdgcn_global_load_lds(                                        \
        (const __attribute__((address_space(1))) void*)(gp),                 \
        (__attribute__((address_space(3))) void*)(lp), 16, 0, 0)

#define TIL 128
#define BKK 32

// 16B-chunk XOR swizzle within a 64B LDS row (involution; 0 conflicts, r5)
__device__ inline int swz(int row, int c) { return c ^ ((row >> 1) & 3); }

// MODE 0: plain  1: causal block-skip (scores)  2: k-clip (PV)
// OUT  0: fp32 C[z][r][c] = v*alpha     OUT 1: bf16 C[r][c] (merged QKV)
template <int MODE, int OUT>
__global__ __launch_bounds__(256) void gemm_bf16(
    const ushort* __restrict__ A, const ushort* __restrict__ B0,
    float* __restrict__ Cf, ushort* __restrict__ Cb,
    int N, int K, int lda, int ldb,
    long long sA, long long sB, long long sC, float alpha)
{
    A  += (long long)blockIdx.z * sA;
    B0 += (long long)blockIdx.z * sB;

    const int m0 = blockIdx.y * TIL;
    const int n0 = blockIdx.x * TIL;
    if (MODE == 1 && n0 > m0 + (TIL - 1)) return;   // fully masked score block
    int kend = K;
    if (MODE == 2) kend = min(K, m0 + TIL);         // attn weights 0 beyond

    __shared__ ushort As[2][TIL * BKK];
    __shared__ ushort Bs[2][TIL * BKK];

    const int tid = threadIdx.x;
    const int l   = tid & 63;
    const int w   = tid >> 6;       // wave 0..3
    const int g   = l >> 4;         // chunk 0..3
    const int r16 = l & 15;
    const int wr  = w >> 1, wc = w & 1;   // wave -> 64x64 quadrant

    f32x4 acc[4][4];
#pragma unroll
    for (int mi = 0; mi < 4; ++mi)
#pragma unroll
        for (int ni = 0; ni < 4; ++ni)
            acc[mi][ni] = (f32x4){0.f, 0.f, 0.f, 0.f};

    // staging: wave w covers rows w*32..+31 (two 16-row GLDS per operand).
    // LDS dest linear; global source chunk pre-swizzled (swz(r+16)==swz(r)+).
    const int srow = w * 32 + (l >> 2);
    const int cg   = swz(srow, l & 3);
    const ushort* gA = A  + (size_t)(m0 + srow) * lda + cg * 8;
    const ushort* gB = B0 + (size_t)(n0 + srow) * ldb + cg * 8;

#define STAGE(buf, k0)                                                       \
    do {                                                                     \
        GLDS(gA + (k0),                     &As[buf][(w * 32) * BKK]);       \
        GLDS(gA + (k0) + (size_t)16 * lda,  &As[buf][(w * 32 + 16) * BKK]);  \
        GLDS(gB + (k0),                     &Bs[buf][(w * 32) * BKK]);       \
        GLDS(gB + (k0) + (size_t)16 * ldb,  &Bs[buf][(w * 32 + 16) * BKK]);  \
    } while (0)

    const int nt = kend / BKK;
    STAGE(0, 0);
    __syncthreads();

    int cur = 0;
    for (int t = 0; t < nt; ++t) {
        if (t + 1 < nt) STAGE(cur ^ 1, (t + 1) * BKK);   // overlap with compute

        i32x4 av[4], bv[4];
#pragma unroll
        for (int mi = 0; mi < 4; ++mi) {
            const int r = wr * 64 + mi * 16 + r16;
            av[mi] = *(const i32x4*)(&As[cur][r * BKK + swz(r, g) * 8]);
        }
#pragma unroll
        for (int ni = 0; ni < 4; ++ni) {
            const int r = wc * 64 + ni * 16 + r16;
            bv[ni] = *(const i32x4*)(&Bs[cur][r * BKK + swz(r, g) * 8]);
        }

#pragma unroll
        for (int mi = 0; mi < 4; ++mi)
#pragma unroll
            for (int ni = 0; ni < 4; ++ni)
                acc[mi][ni] = __builtin_amdgcn_mfma_f32_16x16x32_bf16(
                    as_bf(av[mi]), as_bf(bv[ni]), acc[mi][ni], 0, 0, 0);

        __syncthreads();   // drains next-tile stage (flew under the MFMAs)
        cur ^= 1;
    }
#undef STAGE

    // epilogue: C/D mapping col=lane&15, row=(lane>>4)*4+reg  [m89-verified]
#pragma unroll
    for (int mi = 0; mi < 4; ++mi) {
#pragma unroll
        for (int ni = 0; ni < 4; ++ni) {
#pragma unroll
            for (int rr = 0; rr < 4; ++rr) {
                const int gr = m0 + wr * 64 + mi * 16 + g * 4 + rr;
                const int gc = n0 + wc * 64 + ni * 16 + r16;
                const float v = acc[mi][ni][rr] * alpha;
                if (OUT == 0)
                    Cf[(long long)blockIdx.z * sC + (size_t)gr * N + gc] = v;
                else
                    Cb[(size_t)gr * N + gc] = f2bf(v);
            }
        }
    }
}

// V slice of merged QKV [8192][3072] (cols 2048..3071) -> Vt[b][d][s]
// 64x64 tile via LDS, ushort2 (4B) global accesses both sides.
__global__ __launch_bounds__(256) void transpose_v(
    const ushort* __restrict__ QKV, ushort* __restrict__ Vt)
{
    __shared__ ushort t[64][65];
    const int d0 = blockIdx.x * 64;          // 0..960
    const int r0 = blockIdx.y * 64;          // 0..8128 (b*2048+s), 64 | 2048
    const int tx = threadIdx.x & 31;         // col-pair / s-pair
    const int ty = threadIdx.x >> 5;         // 0..7

#pragma unroll
    for (int p = 0; p < 8; ++p) {
        const int r = ty + p * 8;
        const ushort2 u = *(const ushort2*)(
            QKV + (size_t)(r0 + r) * 3072 + 2048 + d0 + 2 * tx);
        t[r][2 * tx]     = u.x;
        t[r][2 * tx + 1] = u.y;
    }
    __syncthreads();

    const int b = r0 >> 11, s0 = r0 & 2047;
#pragma unroll
    for (int p = 0; p < 8; ++p) {
        const int d = ty + p * 8;
        ushort2 o;
        o.x = t[2 * tx][d];
        o.y = t[2 * tx + 1][d];
        *(ushort2*)(Vt + (size_t)b * 2097152 + (size_t)(d0 + d) * 2048
                    + s0 + 2 * tx) = o;
    }
}

// fp32 scores -> bf16 P in place. Row stride 4096 ushorts (= fp32 row size);
// writes full 2048 bf16 incl. zeroed causal tail.
__global__ __launch_bounds__(256) void softmax_bf16(float* __restrict__ Sc)
{
    const int row = blockIdx.x;
    float* base = Sc + ((size_t)blockIdx.y * 2048 + row) * 2048;
    const int tid = threadIdx.x;

    float v[8];
#pragma unroll
    for (int i = 0; i < 8; ++i) {
        const int j = tid + i * 256;
        v[i] = (j <= row) ? base[j] : -INFINITY;
    }

    __shared__ float red[256];
    float m = -INFINITY;
#pragma unroll
    for (int i = 0; i < 8; ++i) m = fmaxf(m, v[i]);
    red[tid] = m;
    __syncthreads();
    for (int s = 128; s > 0; s >>= 1) {
        if (tid < s) red[tid] = fmaxf(red[tid], red[tid + s]);
        __syncthreads();
    }
    m = red[0];
    __syncthreads();

    float e[8], sum = 0.f;
#pragma unroll
    for (int i = 0; i < 8; ++i) {
        const int j = tid + i * 256;
        e[i] = (j <= row) ? __expf(v[i] - m) : 0.f;
        sum += e[i];
    }
    red[tid] = sum;
    __syncthreads();
    for (int s = 128; s > 0; s >>= 1) {
        if (tid < s) red[tid] += red[tid + s];
        __syncthreads();
    }
    const float inv = 1.f / red[0];

    ushort* pb = (ushort*)base;
#pragma unroll
    for (int i = 0; i < 8; ++i) {
        const int j = tid + i * 256;
        pb[j] = f2bf(e[i] * inv);
    }
}

__global__ void cvt_x(const float4* __restrict__ x, ushort4* __restrict__ o, int n4)
{
    const int i = blockIdx.x * 256 + threadIdx.x;
    if (i < n4) {
        const float4 f = x[i];
        ushort4 u;
        u.x = f2bf(f.x); u.y = f2bf(f.y); u.z = f2bf(f.z); u.w = f2bf(f.w);
        o[i] = u;
    }
}

// W[z] [1024][1024] fp32 -> Wt3 + z*1M : bf16 [n][k] (transpose-convert)
__global__ __launch_bounds__(256) void cvt_wt(const float* __restrict__ Wq,
                                              const float* __restrict__ Wk,
                                              const float* __restrict__ Wv,
                                              ushort* __restrict__ Wt3)
{
    const float* W = (blockIdx.z == 0) ? Wq : (blockIdx.z == 1) ? Wk : Wv;
    ushort* Wt = Wt3 + (size_t)blockIdx.z * 1048576;

    __shared__ float t[32][33];
    const int tx = threadIdx.x & 31, ty = threadIdx.x >> 5;   // ty 0..7
    const int c = blockIdx.x * 32 + tx;
    const int rbase = blockIdx.y * 32;
#pragma unroll
    for (int i = 0; i < 4; ++i)
        t[ty + i * 8][tx] = W[(size_t)(rbase + ty + i * 8) * 1024 + c];
    __syncthreads();
    const int kT = blockIdx.y * 32 + tx;
    const int nT = blockIdx.x * 32;
#pragma unroll
    for (int i = 0; i < 4; ++i)
        Wt[(size_t)(nT + ty + i * 8) * 1024 + kT] = f2bf(t[tx][ty + i * 8]);
}

extern "C" void kernel_launch(void* const* d_in, const int* in_sizes, int n_in,
                              void* d_out, int out_size, void* d_ws, size_t ws_size,
                              hipStream_t stream)
{
    (void)in_sizes; (void)n_in; (void)out_size; (void)ws_size;

    const float* x  = (const float*)d_in[0];
    const float* Wq = (const float*)d_in[1];
    const float* Wk = (const float*)d_in[2];
    const float* Wv = (const float*)d_in[3];
    float* out = (float*)d_out;

    const int NB = 4, S = 2048, D = 1024;
    const long long SD  = (long long)S * D;     // 2,097,152
    const long long NSD = NB * SD;              // 8,388,608
    const long long SS  = (long long)S * S;     // 4,194,304

    // workspace (~150 MB): xb | Wt3 | QKVb | Vt | Sc
    ushort* xb   = (ushort*)d_ws;
    ushort* Wt3  = xb   + NSD;                  // 3*1M ushorts
    ushort* QKVb = Wt3  + 3 * (size_t)D * D;    // [8192][3072] bf16
    ushort* Vt   = QKVb + (size_t)NB * S * 3 * D;
    float*  Sc   = (float*)(Vt + NSD);          // NB*S*S fp32 (P overlays bf16)

    dim3 blk(256);

    // 1) conversions
    cvt_x<<<dim3((unsigned)(NSD / 4 / 256)), blk, 0, stream>>>(
        (const float4*)x, (ushort4*)xb, (int)(NSD / 4));
    cvt_wt<<<dim3(32, 32, 3), blk, 0, stream>>>(Wq, Wk, Wv, Wt3);

    // 2) merged QKV projection: [8192 x 3072 x 1024] -> one bf16 buffer
    dim3 gp(3 * D / TIL, (unsigned)(NB * S / TIL), 1);
    gemm_bf16<0, 1><<<gp, blk, 0, stream>>>(
        xb, Wt3, nullptr, QKVb,
        3 * D, D, D, D, 0, 0, 0, 1.f);

    // 3) V -> Vt[b][d][s]
    transpose_v<<<dim3(D / 64, (unsigned)(NB * S / 64)), blk, 0, stream>>>(
        QKVb, Vt);

    // 4) scores = Q K^T / 32 (strided views of QKVb), causal block-skip
    dim3 gs(S / TIL, S / TIL, NB);
    gemm_bf16<1, 0><<<gs, blk, 0, stream>>>(
        QKVb, QKVb + 1024, Sc, nullptr,
        S, D, 3 * D, 3 * D, (long long)S * 3 * D, (long long)S * 3 * D,
        SS, 0.03125f);

    // 5) softmax fp32 -> bf16 P in place
    softmax_bf16<<<dim3(S, NB), blk, 0, stream>>>(Sc);

    // 6) out = P V^T, k-clipped at the block diagonal
    dim3 gv(D / TIL, S / TIL, NB);
    gemm_bf16<2, 0><<<gv, blk, 0, stream>>>(
        (const ushort*)Sc, Vt, out, nullptr,
        D, S, 2 * S, S, 2 * SS, SD, SD, 1.f);
}

// Round 7
// 199.404 us; speedup vs baseline: 7.1883x; 1.0391x over previous
//
#include <hip/hip_runtime.h>
#include <math.h>

// ---------------------------------------------------------------------------
// CausalAttention — bf16 MFMA pipeline, round 7.
// GEMM core rewritten: BM=128 x BN=256, BK=32, 512 threads = 8 waves (2Mx4N,
// each wave owns 64x64 = 4x4 fragments). Triple-buffered LDS (72 KB), 2-tile
// lookahead with COUNTED vmcnt gates (6/3/0 = 3 loads/thread/tile x tiles in
// flight) + raw s_barrier — loads stay in flight across barriers (T3/T4).
// setprio(1) around the MFMA cluster. Chunk-XOR LDS swizzle (0 conflicts, r5).
// Invariants: gate->barrier proves all waves' tile-t loads landed before any
// read; post-MFMA barrier proves buf free before its t+3 restage. No other
// VMEM ops inside the loop (vmcnt counting stays exact).
// ---------------------------------------------------------------------------

typedef float  f32x4  __attribute__((ext_vector_type(4)));
typedef int    i32x4  __attribute__((ext_vector_type(4)));
typedef __bf16 bf16x8 __attribute__((ext_vector_type(8)));

__device__ inline ushort f2bf(float f) {
    union { float f; unsigned u; } a; a.f = f;
    unsigned u = a.u;
    return (ushort)((u + 0x7fffu + ((u >> 16) & 1u)) >> 16);  // RNE
}
__device__ inline bf16x8 as_bf(i32x4 v) {
    union { i32x4 i; bf16x8 b; } u; u.i = v; return u.b;
}

#define GLDS(gp, lp)                                                         \
    __builtin_amdgcn_global_load_lds(                                        \
        (const __attribute__((address_space(1))) void*)(gp),                 \
        (__attribute__((address_space(3))) void*)(lp), 16, 0, 0)

#define BM 128
#define BN 256
#define BKK 32

// 16B-chunk XOR swizzle within a 64B LDS row (involution; 0 conflicts, r5)
__device__ inline int swz(int row, int c) { return c ^ ((row >> 1) & 3); }

// MODE 0: plain  1: causal block-skip (scores)  2: k-clip (PV)
// OUT  0: fp32 C[z][r][c] = v*alpha     OUT 1: bf16 C[r][c] (merged QKV)
template <int MODE, int OUT>
__global__ __launch_bounds__(512, 4) void gemm_bf16(
    const ushort* __restrict__ A, const ushort* __restrict__ B0,
    float* __restrict__ Cf, ushort* __restrict__ Cb,
    int N, int K, int lda, int ldb,
    long long sA, long long sB, long long sC, float alpha)
{
    A  += (long long)blockIdx.z * sA;
    B0 += (long long)blockIdx.z * sB;

    const int m0 = blockIdx.y * BM;
    const int n0 = blockIdx.x * BN;
    if (MODE == 1 && n0 > m0 + (BM - 1)) return;    // fully masked score block
    int kend = K;
    if (MODE == 2) kend = min(K, m0 + BM);          // attn weights 0 beyond

    __shared__ ushort As[3][BM * BKK];
    __shared__ ushort Bs[3][BN * BKK];

    const int tid = threadIdx.x;
    const int l   = tid & 63;
    const int w   = tid >> 6;             // wave 0..7
    const int g   = l >> 4;               // chunk 0..3
    const int r16 = l & 15;
    const int wr  = w >> 2, wc = w & 3;   // wave -> 64(M) x 64(N) quadrant

    f32x4 acc[4][4];
#pragma unroll
    for (int mi = 0; mi < 4; ++mi)
#pragma unroll
        for (int ni = 0; ni < 4; ++ni)
            acc[mi][ni] = (f32x4){0.f, 0.f, 0.f, 0.f};

    // staging: per tile, per thread: 1 A-load (128 rows) + 2 B-loads (256).
    // Wave w covers rows w*16..+15 per round; global chunk pre-swizzled,
    // LDS dest linear (wave-uniform base + lane*16B).
    const int srow = w * 16 + (l >> 2);             // local row 0..127
    const int cg   = swz(srow, l & 3);
    const ushort* gA = A  + (size_t)(m0 + srow) * lda + cg * 8;
    const ushort* gB = B0 + (size_t)(n0 + srow) * ldb + cg * 8;
    // (row+128 has same swizzle phase: (128>>1)&3 == 0)

#define STAGE(bi, k0)                                                        \
    do {                                                                     \
        GLDS(gA + (k0),                      &As[bi][(w * 16) * BKK]);       \
        GLDS(gB + (k0),                      &Bs[bi][(w * 16) * BKK]);       \
        GLDS(gB + (k0) + (size_t)128 * ldb,  &Bs[bi][(128 + w * 16) * BKK]); \
    } while (0)

    const int nt = kend / BKK;
    STAGE(0, 0);
    if (nt > 1) STAGE(1, BKK);

    int cur = 0;
    for (int t = 0; t < nt; ++t) {
        const int nxt = (cur >= 1) ? cur - 1 : cur + 2;   // (t+2)%3
        if (t + 2 < nt) {
            STAGE(nxt, (t + 2) * BKK);
            asm volatile("s_waitcnt vmcnt(6)" ::: "memory");
        } else if (t + 1 < nt) {
            asm volatile("s_waitcnt vmcnt(3)" ::: "memory");
        } else {
            asm volatile("s_waitcnt vmcnt(0)" ::: "memory");
        }
        __builtin_amdgcn_s_barrier();     // all waves' tile-t loads landed
        asm volatile("" ::: "memory");

        i32x4 av[4], bv[4];
#pragma unroll
        for (int mi = 0; mi < 4; ++mi) {
            const int r = wr * 64 + mi * 16 + r16;
            av[mi] = *(const i32x4*)(&As[cur][r * BKK + swz(r, g) * 8]);
        }
#pragma unroll
        for (int ni = 0; ni < 4; ++ni) {
            const int r = wc * 64 + ni * 16 + r16;
            bv[ni] = *(const i32x4*)(&Bs[cur][r * BKK + swz(r, g) * 8]);
        }

        __builtin_amdgcn_s_setprio(1);
#pragma unroll
        for (int mi = 0; mi < 4; ++mi)
#pragma unroll
            for (int ni = 0; ni < 4; ++ni)
                acc[mi][ni] = __builtin_amdgcn_mfma_f32_16x16x32_bf16(
                    as_bf(av[mi]), as_bf(bv[ni]), acc[mi][ni], 0, 0, 0);
        __builtin_amdgcn_s_setprio(0);

        asm volatile("" ::: "memory");
        __builtin_amdgcn_s_barrier();     // buf[cur] free for restage
        asm volatile("" ::: "memory");
        cur = (cur == 2) ? 0 : cur + 1;
    }
#undef STAGE

    // epilogue: C/D mapping col=lane&15, row=(lane>>4)*4+reg  [m89-verified]
#pragma unroll
    for (int mi = 0; mi < 4; ++mi) {
#pragma unroll
        for (int ni = 0; ni < 4; ++ni) {
#pragma unroll
            for (int rr = 0; rr < 4; ++rr) {
                const int gr = m0 + wr * 64 + mi * 16 + g * 4 + rr;
                const int gc = n0 + wc * 64 + ni * 16 + r16;
                const float v = acc[mi][ni][rr] * alpha;
                if (OUT == 0)
                    Cf[(long long)blockIdx.z * sC + (size_t)gr * N + gc] = v;
                else
                    Cb[(size_t)gr * N + gc] = f2bf(v);
            }
        }
    }
}

// V slice of merged QKV [8192][3072] (cols 2048..3071) -> Vt[b][d][s]
__global__ __launch_bounds__(256) void transpose_v(
    const ushort* __restrict__ QKV, ushort* __restrict__ Vt)
{
    __shared__ ushort t[64][65];
    const int d0 = blockIdx.x * 64;
    const int r0 = blockIdx.y * 64;          // b*2048+s, 64 | 2048
    const int tx = threadIdx.x & 31;
    const int ty = threadIdx.x >> 5;         // 0..7

#pragma unroll
    for (int p = 0; p < 8; ++p) {
        const int r = ty + p * 8;
        const ushort2 u = *(const ushort2*)(
            QKV + (size_t)(r0 + r) * 3072 + 2048 + d0 + 2 * tx);
        t[r][2 * tx]     = u.x;
        t[r][2 * tx + 1] = u.y;
    }
    __syncthreads();

    const int b = r0 >> 11, s0 = r0 & 2047;
#pragma unroll
    for (int p = 0; p < 8; ++p) {
        const int d = ty + p * 8;
        ushort2 o;
        o.x = t[2 * tx][d];
        o.y = t[2 * tx + 1][d];
        *(ushort2*)(Vt + (size_t)b * 2097152 + (size_t)(d0 + d) * 2048
                    + s0 + 2 * tx) = o;
    }
}

// fp32 scores -> bf16 P in place (row stride 4096 ushorts; zeroed tail).
__global__ __launch_bounds__(256) void softmax_bf16(float* __restrict__ Sc)
{
    const int row = blockIdx.x;
    float* base = Sc + ((size_t)blockIdx.y * 2048 + row) * 2048;
    const int tid = threadIdx.x;

    float v[8];
#pragma unroll
    for (int i = 0; i < 8; ++i) {
        const int j = tid + i * 256;
        v[i] = (j <= row) ? base[j] : -INFINITY;
    }

    __shared__ float red[256];
    float m = -INFINITY;
#pragma unroll
    for (int i = 0; i < 8; ++i) m = fmaxf(m, v[i]);
    red[tid] = m;
    __syncthreads();
    for (int s = 128; s > 0; s >>= 1) {
        if (tid < s) red[tid] = fmaxf(red[tid], red[tid + s]);
        __syncthreads();
    }
    m = red[0];
    __syncthreads();

    float e[8], sum = 0.f;
#pragma unroll
    for (int i = 0; i < 8; ++i) {
        const int j = tid + i * 256;
        e[i] = (j <= row) ? __expf(v[i] - m) : 0.f;
        sum += e[i];
    }
    red[tid] = sum;
    __syncthreads();
    for (int s = 128; s > 0; s >>= 1) {
        if (tid < s) red[tid] += red[tid + s];
        __syncthreads();
    }
    const float inv = 1.f / red[0];

    ushort* pb = (ushort*)base;
#pragma unroll
    for (int i = 0; i < 8; ++i) {
        const int j = tid + i * 256;
        pb[j] = f2bf(e[i] * inv);
    }
}

__global__ void cvt_x(const float4* __restrict__ x, ushort4* __restrict__ o, int n4)
{
    const int i = blockIdx.x * 256 + threadIdx.x;
    if (i < n4) {
        const float4 f = x[i];
        ushort4 u;
        u.x = f2bf(f.x); u.y = f2bf(f.y); u.z = f2bf(f.z); u.w = f2bf(f.w);
        o[i] = u;
    }
}

// W[z] [1024][1024] fp32 -> Wt3 + z*1M : bf16 [n][k] (transpose-convert)
__global__ __launch_bounds__(256) void cvt_wt(const float* __restrict__ Wq,
                                              const float* __restrict__ Wk,
                                              const float* __restrict__ Wv,
                                              ushort* __restrict__ Wt3)
{
    const float* W = (blockIdx.z == 0) ? Wq : (blockIdx.z == 1) ? Wk : Wv;
    ushort* Wt = Wt3 + (size_t)blockIdx.z * 1048576;

    __shared__ float t[32][33];
    const int tx = threadIdx.x & 31, ty = threadIdx.x >> 5;
    const int c = blockIdx.x * 32 + tx;
    const int rbase = blockIdx.y * 32;
#pragma unroll
    for (int i = 0; i < 4; ++i)
        t[ty + i * 8][tx] = W[(size_t)(rbase + ty + i * 8) * 1024 + c];
    __syncthreads();
    const int kT = blockIdx.y * 32 + tx;
    const int nT = blockIdx.x * 32;
#pragma unroll
    for (int i = 0; i < 4; ++i)
        Wt[(size_t)(nT + ty + i * 8) * 1024 + kT] = f2bf(t[tx][ty + i * 8]);
}

extern "C" void kernel_launch(void* const* d_in, const int* in_sizes, int n_in,
                              void* d_out, int out_size, void* d_ws, size_t ws_size,
                              hipStream_t stream)
{
    (void)in_sizes; (void)n_in; (void)out_size; (void)ws_size;

    const float* x  = (const float*)d_in[0];
    const float* Wq = (const float*)d_in[1];
    const float* Wk = (const float*)d_in[2];
    const float* Wv = (const float*)d_in[3];
    float* out = (float*)d_out;

    const int NB = 4, S = 2048, D = 1024;
    const long long SD  = (long long)S * D;     // 2,097,152
    const long long NSD = NB * SD;              // 8,388,608
    const long long SS  = (long long)S * S;     // 4,194,304

    // workspace (~150 MB): xb | Wt3 | QKVb | Vt | Sc
    ushort* xb   = (ushort*)d_ws;
    ushort* Wt3  = xb   + NSD;
    ushort* QKVb = Wt3  + 3 * (size_t)D * D;    // [8192][3072] bf16
    ushort* Vt   = QKVb + (size_t)NB * S * 3 * D;
    float*  Sc   = (float*)(Vt + NSD);          // NB*S*S fp32 (P overlays bf16)

    dim3 blk(256), blk5(512);

    // 1) conversions
    cvt_x<<<dim3((unsigned)(NSD / 4 / 256)), blk, 0, stream>>>(
        (const float4*)x, (ushort4*)xb, (int)(NSD / 4));
    cvt_wt<<<dim3(32, 32, 3), blk, 0, stream>>>(Wq, Wk, Wv, Wt3);

    // 2) merged QKV projection: [8192 x 3072 x 1024] -> one bf16 buffer
    dim3 gp(3 * D / BN, (unsigned)(NB * S / BM), 1);
    gemm_bf16<0, 1><<<gp, blk5, 0, stream>>>(
        xb, Wt3, nullptr, QKVb,
        3 * D, D, D, D, 0, 0, 0, 1.f);

    // 3) V -> Vt[b][d][s]
    transpose_v<<<dim3(D / 64, (unsigned)(NB * S / 64)), blk, 0, stream>>>(
        QKVb, Vt);

    // 4) scores = Q K^T / 32 (strided views of QKVb), causal block-skip
    dim3 gs(S / BN, S / BM, NB);
    gemm_bf16<1, 0><<<gs, blk5, 0, stream>>>(
        QKVb, QKVb + 1024, Sc, nullptr,
        S, D, 3 * D, 3 * D, (long long)S * 3 * D, (long long)S * 3 * D,
        SS, 0.03125f);

    // 5) softmax fp32 -> bf16 P in place
    softmax_bf16<<<dim3(S, NB), blk, 0, stream>>>(Sc);

    // 6) out = P V^T, k-clipped at the block diagonal
    dim3 gv(D / BN, S / BM, NB);
    gemm_bf16<2, 0><<<gv, blk5, 0, stream>>>(
        (const ushort*)Sc, Vt, out, nullptr,
        D, S, 2 * S, S, 2 * SS, SD, SD, 1.f);
}